// Round 8
// baseline (511.243 us; speedup 1.0000x reference)
//
#include <hip/hip_runtime.h>

// SelfAttention: x(4,2048,1024) fp32; Linear y = x @ W^T + b for Q,K,V;
// S = QK^T/32; P = softmax(S); O = P V; out = O @ Wo^T + bo.
// R10: ONE persistent kernel (R9 post-mortem: dispatch-sum model closes at
// ~230us vs 297.5 measured -> ~68us = 7 launches x ~10us launch overhead).
//   grid 256 blocks (1/CU, forced by 160KB LDS) x 512 thr; phases separated
//   by device-scope grid barriers (monotonic counter symbol, memset per
//   launch; threadfence + agent-scope atomics = cooperative-groups pattern,
//   handles XCD L2 non-coherence). Engines unchanged from R9 (verified):
//   - g256_tile: 256^2 deep-pipeline, 4 phases/K-step, vmcnt(8), 160KB LDS.
//   - g128_tile: 128x256 3-buf, 2 phases/K-tile, vmcnt(6), 144KB LDS.
//   - T1 XCD swizzle per phase; chunk^(row&7) LDS involution (0 conflicts).
// Phase plan (tiles per block: lg = T1-swizzled blk):
//   0: prep (casts+bias concat, grid-stride)          -> bar1
//   1: QKproj g256 (8x32) THEN VT g128 (32x8) (indep) -> bar2
//   2: QK^T g256 (8,8,4)                              -> bar3
//   3: softmax 32 rows/block                          -> bar4
//   4: PV g128 (4,16,4)                               -> bar5
//   5: out-proj g128 (4,64)
//
// Workspace layout (136 MB, aliased by lifetime) — unchanged from R9:
//   [0,16)MB    x_bf16 [8192][1024]   -> later O (PV output)
//   [16,20)MB   wqk bf16 [2048][1024] (wq|wk fused)
//   [20,22)MB   wv bf16; [22,24)MB wo bf16
//   [24,56)MB   QK bf16 [8192][2048]  -> later P
//   [56,72)MB   VT bf16 [1024][8192]  (batch b at cols [b*2048,(b+1)*2048))
//   [72,136)MB  S fp32 [4][2048][2048]; bqk (8KB) at 72MB dies before S

typedef __bf16 bf16x8 __attribute__((ext_vector_type(8)));
typedef float f32x4 __attribute__((ext_vector_type(4)));
typedef unsigned short ush;

__device__ unsigned int g_bar_cnt;

__device__ __forceinline__ ush f32_to_bf16(float f) {
  unsigned int u = __float_as_uint(f);
  u += 0x7fffu + ((u >> 16) & 1u);   // round-to-nearest-even
  return (ush)(u >> 16);
}

__device__ __forceinline__ ushort4 cvt4(float4 f) {
  ushort4 u;
  u.x = f32_to_bf16(f.x);
  u.y = f32_to_bf16(f.y);
  u.z = f32_to_bf16(f.z);
  u.w = f32_to_bf16(f.w);
  return u;
}

__device__ __forceinline__ void load_lds16(const void* g, void* l) {
  __builtin_amdgcn_global_load_lds(
      (const __attribute__((address_space(1))) void*)g,
      (__attribute__((address_space(3))) void*)l, 16, 0, 0);
}

// Device-scope grid barrier #k (k = 1-based cumulative ordinal, 256 blocks).
// Counter is zeroed by hipMemsetAsync before each kernel launch.
__device__ __forceinline__ void grid_bar(int k) {
  __syncthreads();  // drains each wave's vmem (stores at least in L2)
  if (threadIdx.x == 0) {
    __threadfence();  // agent-scope release: XCD L2 writeback
    __hip_atomic_fetch_add(&g_bar_cnt, 1u, __ATOMIC_ACQ_REL,
                           __HIP_MEMORY_SCOPE_AGENT);
    const unsigned tgt = (unsigned)k * 256u;
    while (__hip_atomic_load(&g_bar_cnt, __ATOMIC_ACQUIRE,
                             __HIP_MEMORY_SCOPE_AGENT) < tgt)
      __builtin_amdgcn_s_sleep(2);
    __threadfence();  // agent-scope acquire: invalidate stale L1/L2
  }
  __syncthreads();
}

// --------------------------------- 256^2 deep-pipeline tile (R9-verified)
// C[bm*256.., bn*256..] = alpha * A[.,K] B[.,K]^T + bias[col]; lds = 160KB.
__device__ void g256_tile(const ush* __restrict__ A, const ush* __restrict__ B,
                          void* __restrict__ C, const float* __restrict__ bias,
                          int N, int K, float alpha, int out_bf16, int lda,
                          int ldb, int bn, int bm, char* smem) {
  ush (*As)[2][8192] = (ush(*)[2][8192])smem;            // 3 bufs = 96KB
  ush (*Bs)[2][8192] = (ush(*)[2][8192])(smem + 98304);  // 2 bufs = 64KB

  const int tid = threadIdx.x;
  const int lane = tid & 63, wave = tid >> 6;
  const int wr = wave >> 2;             // M half (128 rows)
  const int wc = wave & 3;              // N quarter (64 cols)
  const int l16 = lane & 15, quad = lane >> 4;
  const int wbh = wc >> 1;
  const int wbr = (wc & 1) * 64 + l16;
  const int pc0 = (quad ^ (l16 & 7)) * 8;
  const int pc1 = ((4 + quad) ^ (l16 & 7)) * 8;

  const int srow = tid >> 3;
  const int lch = (tid & 7) ^ (srow & 7);
  const ush* gA0 = A + (long long)(bm * 256 + srow) * lda + lch * 8;
  const ush* gB0 = B + (long long)(bn * 256 + srow) * ldb + lch * 8;

  f32x4 acc[8][4] = {};
  bf16x8 af[2][2];
  bf16x8 bf[4][2];

  const int NT = K >> 6;

#define STA(BUF, H, KT)                                                     \
  do {                                                                      \
    const ush* _s = gA0 + (long long)(H) * 128 * lda + (long long)(KT) * 64;\
    char* _d = (char*)&As[BUF][H][0] + wave * 1024;                         \
    load_lds16(_s, _d);                                                     \
    load_lds16(_s + (long long)64 * lda, _d + 8192);                        \
  } while (0)
#define STB(BUF, H, KT)                                                     \
  do {                                                                      \
    const ush* _s = gB0 + (long long)(H) * 128 * ldb + (long long)(KT) * 64;\
    char* _d = (char*)&Bs[BUF][H][0] + wave * 1024;                         \
    load_lds16(_s, _d);                                                     \
    load_lds16(_s + (long long)64 * ldb, _d + 8192);                        \
  } while (0)
#define DSAq(BUF, MIP)                                                      \
  do {                                                                      \
    _Pragma("unroll") for (int m2 = 0; m2 < 2; ++m2) {                      \
      const ush* _r = &As[BUF][wr][(((MIP) * 2 + m2) * 16 + l16) * 64];     \
      af[m2][0] = *(const bf16x8*)(_r + pc0);                               \
      af[m2][1] = *(const bf16x8*)(_r + pc1);                               \
    }                                                                       \
  } while (0)
#define DSBq(BUF)                                                           \
  do {                                                                      \
    _Pragma("unroll") for (int ni = 0; ni < 4; ++ni) {                      \
      const ush* _r = &Bs[BUF][wbh][(wbr + ni * 16) * 64];                  \
      bf[ni][0] = *(const bf16x8*)(_r + pc0);                               \
      bf[ni][1] = *(const bf16x8*)(_r + pc1);                               \
    }                                                                       \
  } while (0)
#define MMq(MIP)                                                            \
  do {                                                                      \
    _Pragma("unroll") for (int m2 = 0; m2 < 2; ++m2)                        \
        _Pragma("unroll") for (int ni = 0; ni < 4; ++ni) {                  \
      f32x4* _a = &acc[(MIP) * 2 + m2][ni];                                 \
      *_a = __builtin_amdgcn_mfma_f32_16x16x32_bf16(af[m2][0], bf[ni][0],   \
                                                    *_a, 0, 0, 0);          \
      *_a = __builtin_amdgcn_mfma_f32_16x16x32_bf16(af[m2][1], bf[ni][1],   \
                                                    *_a, 0, 0, 0);          \
    }                                                                       \
  } while (0)
#define BARx() __builtin_amdgcn_s_barrier()
#define WLGx() asm volatile("s_waitcnt lgkmcnt(0)" ::: "memory")
#define WVM8() asm volatile("s_waitcnt vmcnt(8)" ::: "memory")
#define PR1() __builtin_amdgcn_s_setprio(1)
#define PR0() __builtin_amdgcn_s_setprio(0)

  STA(0, 0, 0);
  STA(0, 1, 0);
  STB(0, 0, 0);
  STB(0, 1, 0);
  STA(1, 0, 1);
  STA(1, 1, 1);
  STB(1, 0, 1);
  STB(1, 1, 1);
  WVM8();
  BARx();

  int a = 0;
  for (int t = 0; t < NT; ++t) {
    const int b = t & 1;
    int a2 = a + 2;
    if (a2 >= 3) a2 -= 3;
    const int kt2 = (t + 2 < NT) ? t + 2 : NT - 1;  // clamped tail restage
    // P1
    DSBq(b);
    DSAq(a, 0);
    STA(a2, 0, kt2);
    BARx();
    WLGx();
    PR1();
    MMq(0);
    PR0();
    BARx();
    // P2
    DSAq(a, 1);
    STA(a2, 1, kt2);
    BARx();
    WLGx();
    PR1();
    MMq(1);
    PR0();
    BARx();
    // P3 (Bs[b] stage-safe: B(t) regs read at P1)
    DSAq(a, 2);
    STB(b, 0, kt2);
    BARx();
    WLGx();
    PR1();
    MMq(2);
    PR0();
    BARx();
    // P4
    DSAq(a, 3);
    STB(b, 1, kt2);
    BARx();
    WLGx();
    PR1();
    MMq(3);
    PR0();
    WVM8();
    BARx();
    ++a;
    if (a == 3) a = 0;
  }
  asm volatile("s_waitcnt vmcnt(0)" ::: "memory");

  const long long orow0 = (long long)bm * 256 + wr * 128 + quad * 4;
  const int ocol0 = bn * 256 + wc * 64 + l16;
  if (out_bf16) {
    ush* Cp = (ush*)C;
#pragma unroll
    for (int mi = 0; mi < 8; ++mi)
#pragma unroll
      for (int ni = 0; ni < 4; ++ni) {
        const int col = ocol0 + ni * 16;
        const float bv = bias ? bias[col] : 0.f;
#pragma unroll
        for (int r = 0; r < 4; ++r) {
          const float o = acc[mi][ni][r] * alpha + bv;
          Cp[(orow0 + mi * 16 + r) * N + col] = f32_to_bf16(o);
        }
      }
  } else {
    float* Cp = (float*)C;
#pragma unroll
    for (int mi = 0; mi < 8; ++mi)
#pragma unroll
      for (int ni = 0; ni < 4; ++ni) {
        const int col = ocol0 + ni * 16;
        const float bv = bias ? bias[col] : 0.f;
#pragma unroll
        for (int r = 0; r < 4; ++r) {
          const float o = acc[mi][ni][r] * alpha + bv;
          Cp[(orow0 + mi * 16 + r) * N + col] = o;
        }
      }
  }
#undef STA
#undef STB
#undef DSAq
#undef DSBq
#undef MMq
#undef BARx
#undef WLGx
#undef WVM8
#undef PR1
#undef PR0
}

// ------------------------------- 128x256 3-buf tile (R9-verified)
// lds = 144KB of smem; bias_row==1 -> bias[row], else bias[col].
__device__ void g128_tile(const ush* __restrict__ A, const ush* __restrict__ B,
                          void* __restrict__ C, const float* __restrict__ bias,
                          int N, int K, float alpha, int out_bf16,
                          int bias_row, int lda, int ldb, int bn, int bm,
                          char* smem) {
  ush (*As)[128][64] = (ush(*)[128][64])smem;            // 48KB
  ush (*Bs)[256][64] = (ush(*)[256][64])(smem + 49152);  // 96KB

  const int tid = threadIdx.x;
  const int lane = tid & 63, wave = tid >> 6;
  const int wr = wave >> 2;
  const int wc = wave & 3;
  const int l16 = lane & 15, quad = lane >> 4;
  const int pc0 = (quad ^ (l16 & 7)) * 8;
  const int pc1 = ((4 + quad) ^ (l16 & 7)) * 8;

  const int srow = tid >> 3;
  const int lch = (tid & 7) ^ (srow & 7);
  const ush* gA0 = A + (long long)(bm * 128 + srow) * lda + lch * 8;
  const ush* gB0 = B + (long long)(bn * 256 + srow) * ldb + lch * 8;

  f32x4 acc[4][4] = {};
  bf16x8 af[2][2];
  bf16x8 bf[4][2];

  const int NT = K >> 6;

#define STG_A(BUF, KT)                                                      \
  do {                                                                      \
    const ush* _s = gA0 + (long long)(KT) * 64;                             \
    char* _d = (char*)&As[BUF][0][0] + wave * 1024;                         \
    load_lds16(_s, _d);                                                     \
    load_lds16(_s + (long long)64 * lda, _d + 8192);                        \
  } while (0)
#define STG_B(BUF, KT, J0, JN)                                              \
  do {                                                                      \
    const ush* _s = gB0 + (long long)(KT) * 64;                             \
    char* _d = (char*)&Bs[BUF][0][0] + wave * 1024;                         \
    _Pragma("unroll") for (int _j = (J0); _j < (JN); ++_j)                  \
        load_lds16(_s + (long long)(_j * 64) * ldb, _d + _j * 8192);        \
  } while (0)
#define DSA(BUF, P)                                                         \
  do {                                                                      \
    _Pragma("unroll") for (int m2 = 0; m2 < 2; ++m2) {                      \
      const ush* _r = &As[BUF][wr * 64 + ((P) * 2 + m2) * 16 + l16][0];     \
      af[m2][0] = *(const bf16x8*)(_r + pc0);                               \
      af[m2][1] = *(const bf16x8*)(_r + pc1);                               \
    }                                                                       \
  } while (0)
#define DSB(BUF)                                                            \
  do {                                                                      \
    _Pragma("unroll") for (int ni = 0; ni < 4; ++ni) {                      \
      const ush* _r = &Bs[BUF][wc * 64 + ni * 16 + l16][0];                 \
      bf[ni][0] = *(const bf16x8*)(_r + pc0);                               \
      bf[ni][1] = *(const bf16x8*)(_r + pc1);                               \
    }                                                                       \
  } while (0)
#define MM(P)                                                               \
  do {                                                                      \
    _Pragma("unroll") for (int m2 = 0; m2 < 2; ++m2)                        \
        _Pragma("unroll") for (int ni = 0; ni < 4; ++ni) {                  \
      f32x4* _a = &acc[(P) * 2 + m2][ni];                                   \
      *_a = __builtin_amdgcn_mfma_f32_16x16x32_bf16(af[m2][0], bf[ni][0],   \
                                                    *_a, 0, 0, 0);          \
      *_a = __builtin_amdgcn_mfma_f32_16x16x32_bf16(af[m2][1], bf[ni][1],   \
                                                    *_a, 0, 0, 0);          \
    }                                                                       \
  } while (0)
#define BAR() __builtin_amdgcn_s_barrier()
#define WLG() asm volatile("s_waitcnt lgkmcnt(0)" ::: "memory")
#define WVM6() asm volatile("s_waitcnt vmcnt(6)" ::: "memory")
#define P1x() __builtin_amdgcn_s_setprio(1)
#define P0x() __builtin_amdgcn_s_setprio(0)

  STG_A(0, 0);
  STG_B(0, 0, 0, 4);
  STG_A(1, 1);
  STG_B(1, 1, 0, 4);
  WVM6();
  BAR();

  int cur = 0;
  for (int t = 0; t < NT; ++t) {
    int b2 = cur + 2;
    if (b2 >= 3) b2 -= 3;
    const int kt = (t + 2 < NT) ? t + 2 : NT - 1;
    // ph0
    DSB(cur);
    DSA(cur, 0);
    STG_A(b2, kt);
    STG_B(b2, kt, 0, 1);
    BAR();
    WLG();
    P1x();
    MM(0);
    P0x();
    BAR();
    // ph1
    DSA(cur, 1);
    STG_B(b2, kt, 1, 4);
    BAR();
    WLG();
    P1x();
    MM(1);
    P0x();
    WVM6();
    BAR();
    ++cur;
    if (cur == 3) cur = 0;
  }
  asm volatile("s_waitcnt vmcnt(0)" ::: "memory");

  const long long orow0 = (long long)bm * 128 + wr * 64 + quad * 4;
  const int ocol0 = bn * 256 + wc * 64 + l16;
  if (out_bf16) {
    ush* Cp = (ush*)C;
#pragma unroll
    for (int mi = 0; mi < 4; ++mi)
#pragma unroll
      for (int ni = 0; ni < 4; ++ni) {
        const int col = ocol0 + ni * 16;
        const float bcol = (bias && !bias_row) ? bias[col] : 0.f;
#pragma unroll
        for (int r = 0; r < 4; ++r) {
          const float bv =
              (bias && bias_row) ? bias[orow0 + mi * 16 + r] : bcol;
          const float o = acc[mi][ni][r] * alpha + bv;
          Cp[(orow0 + mi * 16 + r) * N + col] = f32_to_bf16(o);
        }
      }
  } else {
    float* Cp = (float*)C;
#pragma unroll
    for (int mi = 0; mi < 4; ++mi)
#pragma unroll
      for (int ni = 0; ni < 4; ++ni) {
        const int col = ocol0 + ni * 16;
        const float bcol = (bias && !bias_row) ? bias[col] : 0.f;
#pragma unroll
        for (int r = 0; r < 4; ++r) {
          const float bv =
              (bias && bias_row) ? bias[orow0 + mi * 16 + r] : bcol;
          const float o = acc[mi][ni][r] * alpha + bv;
          Cp[(orow0 + mi * 16 + r) * N + col] = o;
        }
      }
  }
#undef STG_A
#undef STG_B
#undef DSA
#undef DSB
#undef MM
#undef BAR
#undef WLG
#undef WVM6
#undef P1x
#undef P0x
}

// ------------------------------- softmax phase: 32 rows/block, 512 threads
__device__ void softmax_phase(const float* __restrict__ S, ush* __restrict__ P,
                              int blk, char* smem) {
  float* red = (float*)smem;  // [0,8) wave maxes, [8,16) wave sums
  const int t = threadIdx.x;
  const int w = t >> 6, lane = t & 63;
  for (int r = 0; r < 32; ++r) {
    const long long row = (long long)blk * 32 + r;
    const float* s = S + row * 2048;
    float v0 = s[t], v1 = s[t + 512], v2 = s[t + 1024], v3 = s[t + 1536];
    float mx = fmaxf(fmaxf(v0, v1), fmaxf(v2, v3));
#pragma unroll
    for (int o = 32; o >= 1; o >>= 1) mx = fmaxf(mx, __shfl_xor(mx, o));
    if (lane == 0) red[w] = mx;
    __syncthreads();
    mx = red[0];
#pragma unroll
    for (int i = 1; i < 8; ++i) mx = fmaxf(mx, red[i]);
    v0 = __expf(v0 - mx);
    v1 = __expf(v1 - mx);
    v2 = __expf(v2 - mx);
    v3 = __expf(v3 - mx);
    float sum = v0 + v1 + v2 + v3;
#pragma unroll
    for (int o = 32; o >= 1; o >>= 1) sum += __shfl_xor(sum, o);
    if (lane == 0) red[8 + w] = sum;
    __syncthreads();
    sum = red[8];
#pragma unroll
    for (int i = 9; i < 16; ++i) sum += red[i];
    const float inv = 1.0f / sum;
    ush* p = P + row * 2048;
    p[t] = f32_to_bf16(v0 * inv);
    p[t + 512] = f32_to_bf16(v1 * inv);
    p[t + 1024] = f32_to_bf16(v2 * inv);
    p[t + 1536] = f32_to_bf16(v3 * inv);
  }
}

// ----------------------------------------------------------- mega kernel
__global__ __launch_bounds__(512, 1) void fused_all(
    const float4* __restrict__ x, const float4* __restrict__ wq,
    const float4* __restrict__ wk, const float4* __restrict__ wv,
    const float4* __restrict__ wo, const float4* __restrict__ bq4,
    const float4* __restrict__ bk4, const float* __restrict__ bv,
    const float* __restrict__ bo, float* __restrict__ out,
    char* __restrict__ ws) {
  __shared__ __align__(16) char smem[163840];
  const size_t MB = 1ull << 20;
  ush* xb = (ush*)(ws);                 // later O
  ush* wqk = (ush*)(ws + 16 * MB);
  ush* wvb = (ush*)(ws + 20 * MB);
  ush* wob = (ush*)(ws + 22 * MB);
  ush* QKm = (ush*)(ws + 24 * MB);      // later P
  ush* VT = (ush*)(ws + 56 * MB);
  float* S = (float*)(ws + 72 * MB);
  float* bqk = (float*)(ws + 72 * MB);  // dies before S is written
  ush* P = QKm;
  ush* O = xb;

  const int blk = blockIdx.x;
  const int t = threadIdx.x;

  // ---- phase 0: prep (casts + bias concat), grid-stride over float4s
  {
    const int NX = 2097152, NW = 262144;
    ushort4* xbo = (ushort4*)xb;
    ushort4* wqko = (ushort4*)wqk;
    ushort4* wvbo = (ushort4*)wvb;
    ushort4* wobo = (ushort4*)wob;
    float4* bqko = (float4*)bqk;
    for (int i = blk * 512 + t; i < 3146240; i += 131072) {
      if (i < NX) {
        xbo[i] = cvt4(x[i]);
      } else if (i < NX + NW) {
        int j = i - NX;
        wqko[j] = cvt4(wq[j]);
      } else if (i < NX + 2 * NW) {
        int j = i - NX - NW;
        wqko[NW + j] = cvt4(wk[j]);
      } else if (i < NX + 3 * NW) {
        int j = i - NX - 2 * NW;
        wvbo[j] = cvt4(wv[j]);
      } else if (i < NX + 4 * NW) {
        int j = i - NX - 3 * NW;
        wobo[j] = cvt4(wo[j]);
      } else {
        int j = i - NX - 4 * NW;  // < 512
        bqko[j] = (j < 256) ? bq4[j] : bk4[j - 256];
      }
    }
  }
  grid_bar(1);

  // T1 XCD swizzle: 256 tiles/phase, XCD j gets contiguous logical [j*32,..)
  const int lg = (blk & 7) * 32 + (blk >> 3);

  // ---- phase 1: QK projection (256dp) then VT (128x256); both dep prep only
  g256_tile(xb, wqk, QKm, bqk, 2048, 1024, 1.f, 1, 1024, 1024, lg & 7,
            lg >> 3, smem);
  g128_tile(wvb, xb, VT, bv, 8192, 1024, 1.f, 1, 1, 1024, 1024, lg & 31,
            lg >> 5, smem);
  grid_bar(2);

  // ---- phase 2: S = Q K^T / 32 (256dp), batched over 4
  {
    const int bz = lg >> 6;
    const ush* Aq = QKm + (long long)bz * (2048ll * 2048);
    const ush* Bk = QKm + 1024 + (long long)bz * (2048ll * 2048);
    float* Sc = S + (long long)bz * (2048ll * 2048);
    g256_tile(Aq, Bk, Sc, nullptr, 2048, 1024, 0.03125f, 0, 2048, 2048,
              lg & 7, (lg >> 3) & 7, smem);
  }
  grid_bar(3);

  // ---- phase 3: P = softmax rows of S (bf16)
  softmax_phase(S, P, blk, smem);
  grid_bar(4);

  // ---- phase 4: O = P @ V via VT (128x256), batched over 4
  {
    const int bz = lg >> 6;
    const ush* Ap = P + (long long)bz * (2048ll * 2048);
    const ush* Bvt = VT + (long long)bz * 2048;  // batch column offset
    ush* Oc = O + (long long)bz * (2048ll * 1024);
    g128_tile(Ap, Bvt, Oc, nullptr, 1024, 2048, 1.f, 1, 0, 2048, 8192, lg & 3,
              (lg >> 2) & 15, smem);
  }
  grid_bar(5);

  // ---- phase 5: out = O @ Wo^T + bo (fp32)
  g128_tile(O, wob, out, bo, 1024, 1024, 1.f, 0, 0, 1024, 1024, lg & 3,
            lg >> 2, smem);
}

// ----------------------------------------------------------------- launcher
extern "C" void kernel_launch(void* const* d_in, const int* in_sizes, int n_in,
                              void* d_out, int out_size, void* d_ws,
                              size_t ws_size, hipStream_t stream) {
  static void* bar_addr = nullptr;
  if (!bar_addr) (void)hipGetSymbolAddress(&bar_addr, HIP_SYMBOL(g_bar_cnt));
  hipMemsetAsync(bar_addr, 0, sizeof(unsigned int), stream);

  fused_all<<<dim3(256), dim3(512), 0, stream>>>(
      (const float4*)d_in[0], (const float4*)d_in[1], (const float4*)d_in[3],
      (const float4*)d_in[5], (const float4*)d_in[7], (const float4*)d_in[2],
      (const float4*)d_in[4], (const float*)d_in[6], (const float*)d_in[8],
      (float*)d_out, (char*)d_ws);
}

// Round 9
// 346.906 us; speedup vs baseline: 1.4737x; 1.4737x over previous
//
#include <hip/hip_runtime.h>

// SelfAttention: x(4,2048,1024) fp32; Linear y = x @ W^T + b for Q,K,V;
// S = QK^T/32; P = softmax(S); O = P V; out = O @ Wo^T + bo.
// R11 = R9 (best verified, 297.5us) + two safe edits.
//   R10 post-mortem: persistent megakernel regressed (415us vs 230 phase-sum;
//   agent-scope fence pairs at each grid barrier force XCD-L2 wb+inv -> every
//   phase cold; 578MB HBM). Reverted. Kept only the barrier-free fusion:
//   1) fat kernel qkt_vt: QK^T (256 blks, 256dp) + VT (256 blks, 128x256) in
//      ONE launch (VT depends only on prep; QK^T blocks dispatch first ->
//      QK^T tail overlaps VT ramp). Plain stream order, no device sync.
//   2) softmax vectorized: float4 x2 loads + ushort4 x2 stores per thread.
// Engines = R10's __device__ tile fns (correctness-verified in fused_all):
//   g256_tile: 256^2 deep-pipeline, 4 phases/K-step, vmcnt(8), 160KB LDS.
//   g128_tile: 128x256 3-buf, 2 phases/K-tile, vmcnt(6), 144KB LDS.
//   T1 XCD swizzle per launch; chunk^(row&7) LDS involution (0 conflicts).
// Launches (6): prep -> QKproj(k256) -> qkt_vt -> softmax -> PV(k128) -> out(k128).
//
// Workspace layout (136 MB, aliased by lifetime) — unchanged from R9:
//   [0,16)MB    x_bf16 [8192][1024]   -> later O (PV output)
//   [16,20)MB   wqk bf16 [2048][1024] (wq|wk fused)
//   [20,22)MB   wv bf16; [22,24)MB wo bf16
//   [24,56)MB   QK bf16 [8192][2048]  -> later P
//   [56,72)MB   VT bf16 [1024][8192]  (batch b at cols [b*2048,(b+1)*2048))
//   [72,136)MB  S fp32 [4][2048][2048]; bqk (8KB) at 72MB dies before S

typedef __bf16 bf16x8 __attribute__((ext_vector_type(8)));
typedef float f32x4 __attribute__((ext_vector_type(4)));
typedef unsigned short ush;

__device__ __forceinline__ ush f32_to_bf16(float f) {
  unsigned int u = __float_as_uint(f);
  u += 0x7fffu + ((u >> 16) & 1u);   // round-to-nearest-even
  return (ush)(u >> 16);
}

__device__ __forceinline__ ushort4 cvt4(float4 f) {
  ushort4 u;
  u.x = f32_to_bf16(f.x);
  u.y = f32_to_bf16(f.y);
  u.z = f32_to_bf16(f.z);
  u.w = f32_to_bf16(f.w);
  return u;
}

__device__ __forceinline__ void load_lds16(const void* g, void* l) {
  __builtin_amdgcn_global_load_lds(
      (const __attribute__((address_space(1))) void*)g,
      (__attribute__((address_space(3))) void*)l, 16, 0, 0);
}

// ---------------------------------------------------- fused prep kernel
__global__ __launch_bounds__(256) void prep(
    const float4* __restrict__ x, const float4* __restrict__ wq,
    const float4* __restrict__ wk, const float4* __restrict__ wv,
    const float4* __restrict__ wo, const float4* __restrict__ bq,
    const float4* __restrict__ bk, ushort4* __restrict__ xb,
    ushort4* __restrict__ wqk, ushort4* __restrict__ wvb,
    ushort4* __restrict__ wob, float4* __restrict__ bqk) {
  const int NX = 2097152;  // x float4s
  const int NW = 262144;   // one 1024x1024 weight in float4s
  int i = blockIdx.x * 256 + threadIdx.x;
  if (i < NX) {
    xb[i] = cvt4(x[i]);
  } else if (i < NX + NW) {
    int j = i - NX;
    wqk[j] = cvt4(wq[j]);
  } else if (i < NX + 2 * NW) {
    int j = i - NX - NW;
    wqk[NW + j] = cvt4(wk[j]);
  } else if (i < NX + 3 * NW) {
    int j = i - NX - 2 * NW;
    wvb[j] = cvt4(wv[j]);
  } else if (i < NX + 4 * NW) {
    int j = i - NX - 3 * NW;
    wob[j] = cvt4(wo[j]);
  } else if (i < NX + 4 * NW + 512) {
    int j = i - NX - 4 * NW;  // [0,512): bqk float4s (bq 256 | bk 256)
    bqk[j] = (j < 256) ? bq[j] : bk[j - 256];
  }
}

// --------------------------------- 256^2 deep-pipeline tile (verified R10)
// C[bm*256.., bn*256..] = alpha * A[.,K] B[.,K]^T + bias[col]; lds = 160KB.
__device__ void g256_tile(const ush* __restrict__ A, const ush* __restrict__ B,
                          void* __restrict__ C, const float* __restrict__ bias,
                          int N, int K, float alpha, int out_bf16, int lda,
                          int ldb, int bn, int bm, char* smem) {
  ush (*As)[2][8192] = (ush(*)[2][8192])smem;            // 3 bufs = 96KB
  ush (*Bs)[2][8192] = (ush(*)[2][8192])(smem + 98304);  // 2 bufs = 64KB

  const int tid = threadIdx.x;
  const int lane = tid & 63, wave = tid >> 6;
  const int wr = wave >> 2;             // M half (128 rows)
  const int wc = wave & 3;              // N quarter (64 cols)
  const int l16 = lane & 15, quad = lane >> 4;
  const int wbh = wc >> 1;
  const int wbr = (wc & 1) * 64 + l16;
  const int pc0 = (quad ^ (l16 & 7)) * 8;
  const int pc1 = ((4 + quad) ^ (l16 & 7)) * 8;

  const int srow = tid >> 3;
  const int lch = (tid & 7) ^ (srow & 7);
  const ush* gA0 = A + (long long)(bm * 256 + srow) * lda + lch * 8;
  const ush* gB0 = B + (long long)(bn * 256 + srow) * ldb + lch * 8;

  f32x4 acc[8][4] = {};
  bf16x8 af[2][2];
  bf16x8 bf[4][2];

  const int NT = K >> 6;

#define STA(BUF, H, KT)                                                     \
  do {                                                                      \
    const ush* _s = gA0 + (long long)(H) * 128 * lda + (long long)(KT) * 64;\
    char* _d = (char*)&As[BUF][H][0] + wave * 1024;                         \
    load_lds16(_s, _d);                                                     \
    load_lds16(_s + (long long)64 * lda, _d + 8192);                        \
  } while (0)
#define STB(BUF, H, KT)                                                     \
  do {                                                                      \
    const ush* _s = gB0 + (long long)(H) * 128 * ldb + (long long)(KT) * 64;\
    char* _d = (char*)&Bs[BUF][H][0] + wave * 1024;                         \
    load_lds16(_s, _d);                                                     \
    load_lds16(_s + (long long)64 * ldb, _d + 8192);                        \
  } while (0)
#define DSAq(BUF, MIP)                                                      \
  do {                                                                      \
    _Pragma("unroll") for (int m2 = 0; m2 < 2; ++m2) {                      \
      const ush* _r = &As[BUF][wr][(((MIP) * 2 + m2) * 16 + l16) * 64];     \
      af[m2][0] = *(const bf16x8*)(_r + pc0);                               \
      af[m2][1] = *(const bf16x8*)(_r + pc1);                               \
    }                                                                       \
  } while (0)
#define DSBq(BUF)                                                           \
  do {                                                                      \
    _Pragma("unroll") for (int ni = 0; ni < 4; ++ni) {                      \
      const ush* _r = &Bs[BUF][wbh][(wbr + ni * 16) * 64];                  \
      bf[ni][0] = *(const bf16x8*)(_r + pc0);                               \
      bf[ni][1] = *(const bf16x8*)(_r + pc1);                               \
    }                                                                       \
  } while (0)
#define MMq(MIP)                                                            \
  do {                                                                      \
    _Pragma("unroll") for (int m2 = 0; m2 < 2; ++m2)                        \
        _Pragma("unroll") for (int ni = 0; ni < 4; ++ni) {                  \
      f32x4* _a = &acc[(MIP) * 2 + m2][ni];                                 \
      *_a = __builtin_amdgcn_mfma_f32_16x16x32_bf16(af[m2][0], bf[ni][0],   \
                                                    *_a, 0, 0, 0);          \
      *_a = __builtin_amdgcn_mfma_f32_16x16x32_bf16(af[m2][1], bf[ni][1],   \
                                                    *_a, 0, 0, 0);          \
    }                                                                       \
  } while (0)
#define BARx() __builtin_amdgcn_s_barrier()
#define WLGx() asm volatile("s_waitcnt lgkmcnt(0)" ::: "memory")
#define WVM8() asm volatile("s_waitcnt vmcnt(8)" ::: "memory")
#define PR1() __builtin_amdgcn_s_setprio(1)
#define PR0() __builtin_amdgcn_s_setprio(0)

  STA(0, 0, 0);
  STA(0, 1, 0);
  STB(0, 0, 0);
  STB(0, 1, 0);
  STA(1, 0, 1);
  STA(1, 1, 1);
  STB(1, 0, 1);
  STB(1, 1, 1);
  WVM8();
  BARx();

  int a = 0;
  for (int t = 0; t < NT; ++t) {
    const int b = t & 1;
    int a2 = a + 2;
    if (a2 >= 3) a2 -= 3;
    const int kt2 = (t + 2 < NT) ? t + 2 : NT - 1;  // clamped tail restage
    // P1
    DSBq(b);
    DSAq(a, 0);
    STA(a2, 0, kt2);
    BARx();
    WLGx();
    PR1();
    MMq(0);
    PR0();
    BARx();
    // P2
    DSAq(a, 1);
    STA(a2, 1, kt2);
    BARx();
    WLGx();
    PR1();
    MMq(1);
    PR0();
    BARx();
    // P3 (Bs[b] stage-safe: B(t) regs read at P1)
    DSAq(a, 2);
    STB(b, 0, kt2);
    BARx();
    WLGx();
    PR1();
    MMq(2);
    PR0();
    BARx();
    // P4
    DSAq(a, 3);
    STB(b, 1, kt2);
    BARx();
    WLGx();
    PR1();
    MMq(3);
    PR0();
    WVM8();
    BARx();
    ++a;
    if (a == 3) a = 0;
  }
  asm volatile("s_waitcnt vmcnt(0)" ::: "memory");

  const long long orow0 = (long long)bm * 256 + wr * 128 + quad * 4;
  const int ocol0 = bn * 256 + wc * 64 + l16;
  if (out_bf16) {
    ush* Cp = (ush*)C;
#pragma unroll
    for (int mi = 0; mi < 8; ++mi)
#pragma unroll
      for (int ni = 0; ni < 4; ++ni) {
        const int col = ocol0 + ni * 16;
        const float bv = bias ? bias[col] : 0.f;
#pragma unroll
        for (int r = 0; r < 4; ++r) {
          const float o = acc[mi][ni][r] * alpha + bv;
          Cp[(orow0 + mi * 16 + r) * N + col] = f32_to_bf16(o);
        }
      }
  } else {
    float* Cp = (float*)C;
#pragma unroll
    for (int mi = 0; mi < 8; ++mi)
#pragma unroll
      for (int ni = 0; ni < 4; ++ni) {
        const int col = ocol0 + ni * 16;
        const float bv = bias ? bias[col] : 0.f;
#pragma unroll
        for (int r = 0; r < 4; ++r) {
          const float o = acc[mi][ni][r] * alpha + bv;
          Cp[(orow0 + mi * 16 + r) * N + col] = o;
        }
      }
  }
#undef STA
#undef STB
#undef DSAq
#undef DSBq
#undef MMq
#undef BARx
#undef WLGx
#undef WVM8
#undef PR1
#undef PR0
}

// ------------------------------- 128x256 3-buf tile (verified R10)
// lds = 144KB of smem; bias_row==1 -> bias[row], else bias[col].
__device__ void g128_tile(const ush* __restrict__ A, const ush* __restrict__ B,
                          void* __restrict__ C, const float* __restrict__ bias,
                          int N, int K, float alpha, int out_bf16,
                          int bias_row, int lda, int ldb, int bn, int bm,
                          char* smem) {
  ush (*As)[128][64] = (ush(*)[128][64])smem;            // 48KB
  ush (*Bs)[256][64] = (ush(*)[256][64])(smem + 49152);  // 96KB

  const int tid = threadIdx.x;
  const int lane = tid & 63, wave = tid >> 6;
  const int wr = wave >> 2;
  const int wc = wave & 3;
  const int l16 = lane & 15, quad = lane >> 4;
  const int pc0 = (quad ^ (l16 & 7)) * 8;
  const int pc1 = ((4 + quad) ^ (l16 & 7)) * 8;

  const int srow = tid >> 3;
  const int lch = (tid & 7) ^ (srow & 7);
  const ush* gA0 = A + (long long)(bm * 128 + srow) * lda + lch * 8;
  const ush* gB0 = B + (long long)(bn * 256 + srow) * ldb + lch * 8;

  f32x4 acc[4][4] = {};
  bf16x8 af[2][2];
  bf16x8 bf[4][2];

  const int NT = K >> 6;

#define STG_A(BUF, KT)                                                      \
  do {                                                                      \
    const ush* _s = gA0 + (long long)(KT) * 64;                             \
    char* _d = (char*)&As[BUF][0][0] + wave * 1024;                         \
    load_lds16(_s, _d);                                                     \
    load_lds16(_s + (long long)64 * lda, _d + 8192);                        \
  } while (0)
#define STG_B(BUF, KT, J0, JN)                                              \
  do {                                                                      \
    const ush* _s = gB0 + (long long)(KT) * 64;                             \
    char* _d = (char*)&Bs[BUF][0][0] + wave * 1024;                         \
    _Pragma("unroll") for (int _j = (J0); _j < (JN); ++_j)                  \
        load_lds16(_s + (long long)(_j * 64) * ldb, _d + _j * 8192);        \
  } while (0)
#define DSA(BUF, P)                                                         \
  do {                                                                      \
    _Pragma("unroll") for (int m2 = 0; m2 < 2; ++m2) {                      \
      const ush* _r = &As[BUF][wr * 64 + ((P) * 2 + m2) * 16 + l16][0];     \
      af[m2][0] = *(const bf16x8*)(_r + pc0);                               \
      af[m2][1] = *(const bf16x8*)(_r + pc1);                               \
    }                                                                       \
  } while (0)
#define DSB(BUF)                                                            \
  do {                                                                      \
    _Pragma("unroll") for (int ni = 0; ni < 4; ++ni) {                      \
      const ush* _r = &Bs[BUF][wc * 64 + ni * 16 + l16][0];                 \
      bf[ni][0] = *(const bf16x8*)(_r + pc0);                               \
      bf[ni][1] = *(const bf16x8*)(_r + pc1);                               \
    }                                                                       \
  } while (0)
#define MM(P)                                                               \
  do {                                                                      \
    _Pragma("unroll") for (int m2 = 0; m2 < 2; ++m2)                        \
        _Pragma("unroll") for (int ni = 0; ni < 4; ++ni) {                  \
      f32x4* _a = &acc[(P) * 2 + m2][ni];                                   \
      *_a = __builtin_amdgcn_mfma_f32_16x16x32_bf16(af[m2][0], bf[ni][0],   \
                                                    *_a, 0, 0, 0);          \
      *_a = __builtin_amdgcn_mfma_f32_16x16x32_bf16(af[m2][1], bf[ni][1],   \
                                                    *_a, 0, 0, 0);          \
    }                                                                       \
  } while (0)
#define BAR() __builtin_amdgcn_s_barrier()
#define WLG() asm volatile("s_waitcnt lgkmcnt(0)" ::: "memory")
#define WVM6() asm volatile("s_waitcnt vmcnt(6)" ::: "memory")
#define P1x() __builtin_amdgcn_s_setprio(1)
#define P0x() __builtin_amdgcn_s_setprio(0)

  STG_A(0, 0);
  STG_B(0, 0, 0, 4);
  STG_A(1, 1);
  STG_B(1, 1, 0, 4);
  WVM6();
  BAR();

  int cur = 0;
  for (int t = 0; t < NT; ++t) {
    int b2 = cur + 2;
    if (b2 >= 3) b2 -= 3;
    const int kt = (t + 2 < NT) ? t + 2 : NT - 1;
    // ph0
    DSB(cur);
    DSA(cur, 0);
    STG_A(b2, kt);
    STG_B(b2, kt, 0, 1);
    BAR();
    WLG();
    P1x();
    MM(0);
    P0x();
    BAR();
    // ph1
    DSA(cur, 1);
    STG_B(b2, kt, 1, 4);
    BAR();
    WLG();
    P1x();
    MM(1);
    P0x();
    WVM6();
    BAR();
    ++cur;
    if (cur == 3) cur = 0;
  }
  asm volatile("s_waitcnt vmcnt(0)" ::: "memory");

  const long long orow0 = (long long)bm * 128 + wr * 64 + quad * 4;
  const int ocol0 = bn * 256 + wc * 64 + l16;
  if (out_bf16) {
    ush* Cp = (ush*)C;
#pragma unroll
    for (int mi = 0; mi < 4; ++mi)
#pragma unroll
      for (int ni = 0; ni < 4; ++ni) {
        const int col = ocol0 + ni * 16;
        const float bcol = (bias && !bias_row) ? bias[col] : 0.f;
#pragma unroll
        for (int r = 0; r < 4; ++r) {
          const float bv =
              (bias && bias_row) ? bias[orow0 + mi * 16 + r] : bcol;
          const float o = acc[mi][ni][r] * alpha + bv;
          Cp[(orow0 + mi * 16 + r) * N + col] = f32_to_bf16(o);
        }
      }
  } else {
    float* Cp = (float*)C;
#pragma unroll
    for (int mi = 0; mi < 4; ++mi)
#pragma unroll
      for (int ni = 0; ni < 4; ++ni) {
        const int col = ocol0 + ni * 16;
        const float bcol = (bias && !bias_row) ? bias[col] : 0.f;
#pragma unroll
        for (int r = 0; r < 4; ++r) {
          const float bv =
              (bias && bias_row) ? bias[orow0 + mi * 16 + r] : bcol;
          const float o = acc[mi][ni][r] * alpha + bv;
          Cp[(orow0 + mi * 16 + r) * N + col] = o;
        }
      }
  }
#undef STG_A
#undef STG_B
#undef DSA
#undef DSB
#undef MM
#undef BAR
#undef WLG
#undef WVM6
#undef P1x
#undef P0x
}

// ---------------- standalone wrappers (T1 bijective XCD swizzle, R9 form)
__global__ __launch_bounds__(512, 2) void k256(
    const ush* __restrict__ A, const ush* __restrict__ B, void* __restrict__ C,
    const float* __restrict__ bias, int N, int K, float alpha, int out_bf16,
    int lda, int ldb, long long sA, long long sB, long long sC) {
  __shared__ __align__(16) char smem[163840];
  const int hw = blockIdx.x + gridDim.x * (blockIdx.y + gridDim.y * blockIdx.z);
  const int nwg = gridDim.x * gridDim.y * gridDim.z;
  const int lg = (hw & 7) * (nwg >> 3) + (hw >> 3);
  const int bn = lg % gridDim.x;
  const int rem = lg / gridDim.x;
  const int bm = rem % gridDim.y;
  const int bz = rem / gridDim.y;
  void* Cb = out_bf16 ? (void*)((ush*)C + (long long)bz * sC)
                      : (void*)((float*)C + (long long)bz * sC);
  g256_tile(A + (long long)bz * sA, B + (long long)bz * sB, Cb, bias, N, K,
            alpha, out_bf16, lda, ldb, bn, bm, smem);
}

__global__ __launch_bounds__(512, 2) void k128(
    const ush* __restrict__ A, const ush* __restrict__ B, void* __restrict__ C,
    const float* __restrict__ bias, int N, int K, float alpha, int out_bf16,
    int bias_row, int lda, int ldb, long long sA, long long sB, long long sC) {
  __shared__ __align__(16) char smem[147456];
  const int hw = blockIdx.x + gridDim.x * (blockIdx.y + gridDim.y * blockIdx.z);
  const int nwg = gridDim.x * gridDim.y * gridDim.z;
  const int lg = (hw & 7) * (nwg >> 3) + (hw >> 3);
  const int bn = lg % gridDim.x;
  const int rem = lg / gridDim.x;
  const int bm = rem % gridDim.y;
  const int bz = rem / gridDim.y;
  void* Cb = out_bf16 ? (void*)((ush*)C + (long long)bz * sC)
                      : (void*)((float*)C + (long long)bz * sC);
  g128_tile(A + (long long)bz * sA, B + (long long)bz * sB, Cb, bias, N, K,
            alpha, out_bf16, bias_row, lda, ldb, bn, bm, smem);
}

// ---- fat kernel: QK^T (blocks 0..255, dispatched first) + VT (256..511).
// Both runnable after QKproj; VT depends only on prep. Tail overlap for free.
__global__ __launch_bounds__(512, 2) void qkt_vt(
    const ush* __restrict__ QKm, float* __restrict__ S,
    const ush* __restrict__ wvb, const ush* __restrict__ xb,
    ush* __restrict__ VT, const float* __restrict__ bv) {
  __shared__ __align__(16) char smem[163840];
  const int blk = blockIdx.x;
  if (blk < 256) {
    // QK^T: grid-equivalent (8,8,4); S = Q K^T / 32, fp32
    const int lg = (blk & 7) * 32 + (blk >> 3);
    const int bn = lg & 7, bm = (lg >> 3) & 7, bz = lg >> 6;
    const long long off = (long long)bz * (2048ll * 2048);
    g256_tile(QKm + off, QKm + 1024 + off, (void*)(S + off), nullptr, 2048,
              1024, 0.03125f, 0, 2048, 2048, bn, bm, smem);
  } else {
    // VT[d][s] = sum_k w_v[d,k] x[s,k] + bv[d]; grid-equivalent (32,8)
    const int b2 = blk - 256;
    const int lg = (b2 & 7) * 32 + (b2 >> 3);
    const int bn = lg & 31, bm = lg >> 5;
    g128_tile(wvb, xb, VT, bv, 8192, 1024, 1.f, 1, 1, 1024, 1024, bn, bm,
              smem);
  }
}

// ------------------------------------------------- row softmax (vectorized)
// S: [8192][2048] fp32 -> P bf16. One block/row; float4 x2 in, ushort4 x2 out.
__global__ __launch_bounds__(256) void softmax_rows(
    const float* __restrict__ S, ush* __restrict__ P) {
  const long long row = blockIdx.x;
  const float4* s4 = (const float4*)(S + row * 2048);
  const int t = threadIdx.x;
  float4 a = s4[t], b = s4[t + 256];
  float mx = fmaxf(fmaxf(fmaxf(a.x, a.y), fmaxf(a.z, a.w)),
                   fmaxf(fmaxf(b.x, b.y), fmaxf(b.z, b.w)));
#pragma unroll
  for (int o = 32; o >= 1; o >>= 1) mx = fmaxf(mx, __shfl_xor(mx, o));
  __shared__ float red[4], red2[4];
  if ((t & 63) == 0) red[t >> 6] = mx;
  __syncthreads();
  mx = fmaxf(fmaxf(red[0], red[1]), fmaxf(red[2], red[3]));
  a.x = __expf(a.x - mx);
  a.y = __expf(a.y - mx);
  a.z = __expf(a.z - mx);
  a.w = __expf(a.w - mx);
  b.x = __expf(b.x - mx);
  b.y = __expf(b.y - mx);
  b.z = __expf(b.z - mx);
  b.w = __expf(b.w - mx);
  float sum = (a.x + a.y) + (a.z + a.w) + (b.x + b.y) + (b.z + b.w);
#pragma unroll
  for (int o = 32; o >= 1; o >>= 1) sum += __shfl_xor(sum, o);
  if ((t & 63) == 0) red2[t >> 6] = sum;
  __syncthreads();
  sum = red2[0] + red2[1] + red2[2] + red2[3];
  const float inv = 1.0f / sum;
  ushort4 ua, ub;
  ua.x = f32_to_bf16(a.x * inv);
  ua.y = f32_to_bf16(a.y * inv);
  ua.z = f32_to_bf16(a.z * inv);
  ua.w = f32_to_bf16(a.w * inv);
  ub.x = f32_to_bf16(b.x * inv);
  ub.y = f32_to_bf16(b.y * inv);
  ub.z = f32_to_bf16(b.z * inv);
  ub.w = f32_to_bf16(b.w * inv);
  ushort4* p4 = (ushort4*)(P + row * 2048);
  p4[t] = ua;
  p4[t + 256] = ub;
}

// ----------------------------------------------------------------- launcher
extern "C" void kernel_launch(void* const* d_in, const int* in_sizes, int n_in,
                              void* d_out, int out_size, void* d_ws,
                              size_t ws_size, hipStream_t stream) {
  const float* x = (const float*)d_in[0];
  const float* wq = (const float*)d_in[1];
  const float* bq = (const float*)d_in[2];
  const float* wk = (const float*)d_in[3];
  const float* bk = (const float*)d_in[4];
  const float* wv = (const float*)d_in[5];
  const float* bv = (const float*)d_in[6];
  const float* wo = (const float*)d_in[7];
  const float* bo = (const float*)d_in[8];
  float* out = (float*)d_out;
  char* ws = (char*)d_ws;
  const size_t MB = 1ull << 20;

  ush* xb  = (ush*)(ws + 0);        // 16MB, later O
  ush* wqk = (ush*)(ws + 16 * MB);  // 4MB [2048][1024]
  ush* wvb = (ush*)(ws + 20 * MB);  // 2MB
  ush* wob = (ush*)(ws + 22 * MB);  // 2MB
  ush* QKm = (ush*)(ws + 24 * MB);  // 32MB [8192][2048]
  ush* VT  = (ush*)(ws + 56 * MB);  // 16MB [1024][8192]
  float* S   = (float*)(ws + 72 * MB);  // 64MB
  float* bqk = (float*)(ws + 72 * MB);  // 8KB, dies before S is written
  ush* P = QKm;                         // 32MB over QK
  ush* O = xb;                          // 16MB over x_bf16

  // 1) fused prep: all casts + bias concat
  prep<<<dim3(12290), dim3(256), 0, stream>>>(
      (const float4*)x, (const float4*)wq, (const float4*)wk,
      (const float4*)wv, (const float4*)wo, (const float4*)bq,
      (const float4*)bk, (ushort4*)xb, (ushort4*)wqk, (ushort4*)wvb,
      (ushort4*)wob, (float4*)bqk);

  // 2) fused QK projection: [8192,2048] = x_bf16 @ [wq;wk]^T + bqk
  //    256dp engine, grid 8x32 = 256 blocks = 1 full round
  k256<<<dim3(8, 32, 1), dim3(512), 0, stream>>>(
      xb, wqk, QKm, bqk, 2048, 1024, 1.f, 1, 1024, 1024, 0, 0, 0);

  // 3) fat kernel: QK^T (256dp, blocks 0-255) + VT (128x256, blocks 256-511)
  qkt_vt<<<dim3(512), dim3(512), 0, stream>>>(QKm, S, wvb, xb, VT, bv);

  // 4) P = softmax rows of S (bf16), vectorized
  softmax_rows<<<dim3(8192), dim3(256), 0, stream>>>(S, P);

  // 5) O = P @ V via VT (128x256), batched over 4; grid 4x16x4 = 256 blocks
  k128<<<dim3(4, 16, 4), dim3(512), 0, stream>>>(
      P, VT, O, nullptr, 1024, 2048, 1.f, 1, 0, 2048, 8192, 2048ll * 2048,
      2048ll, 2048ll * 1024);

  // 6) out = O @ Wo^T + bo (fp32); grid 4x64 = 256 blocks
  k128<<<dim3(4, 64, 1), dim3(512), 0, stream>>>(
      O, wob, out, bo, 1024, 1024, 1.f, 0, 0, 1024, 1024, 0, 0, 0);
}

// Round 10
// 293.233 us; speedup vs baseline: 1.7435x; 1.1830x over previous
//
#include <hip/hip_runtime.h>

// SelfAttention: x(4,2048,1024) fp32; Linear y = x @ W^T + b for Q,K,V;
// S = QK^T/32; P = softmax(S); O = P V; out = O @ Wo^T + bo.
// R12 = R9 (best verified, 297.5us) + vectorized softmax (verified in R11).
//   R10 post-mortem: persistent megakernel -49%: grid-barrier fences force
//   XCD-L2 wb+inv -> all phases cold (578MB HBM).
//   R11 post-mortem: fat qkt_vt kernel -17%: mixed workloads co-resident
//   break T1 XCD mapping + thrash L2 (FETCH 117MB vs 53 expected).
//   => intra-stream packing loses more in cache/placement than launch gaps
//   save. Keep 6 separate launches; only safe R11 piece retained: softmax
//   with float4 x2 loads / ushort4 x2 stores (G13).
// Engines (verified, unchanged):
//   g256_tile: 256^2 deep-pipeline, 4 phases/K-step, vmcnt(8), 160KB LDS.
//   g128_tile: 128x256 3-buf, 2 phases/K-tile, vmcnt(6), 144KB LDS.
//   T1 bijective XCD swizzle per launch; chunk^(row&7) LDS involution
//   (SQ_LDS_BANK_CONFLICT == 0 measured every round).
// Launches (7): prep -> QKproj(k256) -> VT(k128) -> QK^T(k256) -> softmax
//   -> PV(k128) -> out(k128).
//
// Workspace layout (136 MB, aliased by lifetime):
//   [0,16)MB    x_bf16 [8192][1024]   -> later O (PV output)
//   [16,20)MB   wqk bf16 [2048][1024] (wq|wk fused)
//   [20,22)MB   wv bf16; [22,24)MB wo bf16
//   [24,56)MB   QK bf16 [8192][2048]  -> later P
//   [56,72)MB   VT bf16 [1024][8192]  (batch b at cols [b*2048,(b+1)*2048))
//   [72,136)MB  S fp32 [4][2048][2048]; bqk (8KB) at 72MB dies before S

typedef __bf16 bf16x8 __attribute__((ext_vector_type(8)));
typedef float f32x4 __attribute__((ext_vector_type(4)));
typedef unsigned short ush;

__device__ __forceinline__ ush f32_to_bf16(float f) {
  unsigned int u = __float_as_uint(f);
  u += 0x7fffu + ((u >> 16) & 1u);   // round-to-nearest-even
  return (ush)(u >> 16);
}

__device__ __forceinline__ ushort4 cvt4(float4 f) {
  ushort4 u;
  u.x = f32_to_bf16(f.x);
  u.y = f32_to_bf16(f.y);
  u.z = f32_to_bf16(f.z);
  u.w = f32_to_bf16(f.w);
  return u;
}

__device__ __forceinline__ void load_lds16(const void* g, void* l) {
  __builtin_amdgcn_global_load_lds(
      (const __attribute__((address_space(1))) void*)g,
      (__attribute__((address_space(3))) void*)l, 16, 0, 0);
}

// ---------------------------------------------------- fused prep kernel
__global__ __launch_bounds__(256) void prep(
    const float4* __restrict__ x, const float4* __restrict__ wq,
    const float4* __restrict__ wk, const float4* __restrict__ wv,
    const float4* __restrict__ wo, const float4* __restrict__ bq,
    const float4* __restrict__ bk, ushort4* __restrict__ xb,
    ushort4* __restrict__ wqk, ushort4* __restrict__ wvb,
    ushort4* __restrict__ wob, float4* __restrict__ bqk) {
  const int NX = 2097152;  // x float4s
  const int NW = 262144;   // one 1024x1024 weight in float4s
  int i = blockIdx.x * 256 + threadIdx.x;
  if (i < NX) {
    xb[i] = cvt4(x[i]);
  } else if (i < NX + NW) {
    int j = i - NX;
    wqk[j] = cvt4(wq[j]);
  } else if (i < NX + 2 * NW) {
    int j = i - NX - NW;
    wqk[NW + j] = cvt4(wk[j]);
  } else if (i < NX + 3 * NW) {
    int j = i - NX - 2 * NW;
    wvb[j] = cvt4(wv[j]);
  } else if (i < NX + 4 * NW) {
    int j = i - NX - 3 * NW;
    wob[j] = cvt4(wo[j]);
  } else if (i < NX + 4 * NW + 512) {
    int j = i - NX - 4 * NW;  // [0,512): bqk float4s (bq 256 | bk 256)
    bqk[j] = (j < 256) ? bq[j] : bk[j - 256];
  }
}

// --------------------------------- 256^2 deep-pipeline tile (verified)
// C[bm*256.., bn*256..] = alpha * A[.,K] B[.,K]^T + bias[col]; lds = 160KB.
__device__ void g256_tile(const ush* __restrict__ A, const ush* __restrict__ B,
                          void* __restrict__ C, const float* __restrict__ bias,
                          int N, int K, float alpha, int out_bf16, int lda,
                          int ldb, int bn, int bm, char* smem) {
  ush (*As)[2][8192] = (ush(*)[2][8192])smem;            // 3 bufs = 96KB
  ush (*Bs)[2][8192] = (ush(*)[2][8192])(smem + 98304);  // 2 bufs = 64KB

  const int tid = threadIdx.x;
  const int lane = tid & 63, wave = tid >> 6;
  const int wr = wave >> 2;             // M half (128 rows)
  const int wc = wave & 3;              // N quarter (64 cols)
  const int l16 = lane & 15, quad = lane >> 4;
  const int wbh = wc >> 1;
  const int wbr = (wc & 1) * 64 + l16;
  const int pc0 = (quad ^ (l16 & 7)) * 8;
  const int pc1 = ((4 + quad) ^ (l16 & 7)) * 8;

  const int srow = tid >> 3;
  const int lch = (tid & 7) ^ (srow & 7);
  const ush* gA0 = A + (long long)(bm * 256 + srow) * lda + lch * 8;
  const ush* gB0 = B + (long long)(bn * 256 + srow) * ldb + lch * 8;

  f32x4 acc[8][4] = {};
  bf16x8 af[2][2];
  bf16x8 bf[4][2];

  const int NT = K >> 6;

#define STA(BUF, H, KT)                                                     \
  do {                                                                      \
    const ush* _s = gA0 + (long long)(H) * 128 * lda + (long long)(KT) * 64;\
    char* _d = (char*)&As[BUF][H][0] + wave * 1024;                         \
    load_lds16(_s, _d);                                                     \
    load_lds16(_s + (long long)64 * lda, _d + 8192);                        \
  } while (0)
#define STB(BUF, H, KT)                                                     \
  do {                                                                      \
    const ush* _s = gB0 + (long long)(H) * 128 * ldb + (long long)(KT) * 64;\
    char* _d = (char*)&Bs[BUF][H][0] + wave * 1024;                         \
    load_lds16(_s, _d);                                                     \
    load_lds16(_s + (long long)64 * ldb, _d + 8192);                        \
  } while (0)
#define DSAq(BUF, MIP)                                                      \
  do {                                                                      \
    _Pragma("unroll") for (int m2 = 0; m2 < 2; ++m2) {                      \
      const ush* _r = &As[BUF][wr][(((MIP) * 2 + m2) * 16 + l16) * 64];     \
      af[m2][0] = *(const bf16x8*)(_r + pc0);                               \
      af[m2][1] = *(const bf16x8*)(_r + pc1);                               \
    }                                                                       \
  } while (0)
#define DSBq(BUF)                                                           \
  do {                                                                      \
    _Pragma("unroll") for (int ni = 0; ni < 4; ++ni) {                      \
      const ush* _r = &Bs[BUF][wbh][(wbr + ni * 16) * 64];                  \
      bf[ni][0] = *(const bf16x8*)(_r + pc0);                               \
      bf[ni][1] = *(const bf16x8*)(_r + pc1);                               \
    }                                                                       \
  } while (0)
#define MMq(MIP)                                                            \
  do {                                                                      \
    _Pragma("unroll") for (int m2 = 0; m2 < 2; ++m2)                        \
        _Pragma("unroll") for (int ni = 0; ni < 4; ++ni) {                  \
      f32x4* _a = &acc[(MIP) * 2 + m2][ni];                                 \
      *_a = __builtin_amdgcn_mfma_f32_16x16x32_bf16(af[m2][0], bf[ni][0],   \
                                                    *_a, 0, 0, 0);          \
      *_a = __builtin_amdgcn_mfma_f32_16x16x32_bf16(af[m2][1], bf[ni][1],   \
                                                    *_a, 0, 0, 0);          \
    }                                                                       \
  } while (0)
#define BARx() __builtin_amdgcn_s_barrier()
#define WLGx() asm volatile("s_waitcnt lgkmcnt(0)" ::: "memory")
#define WVM8() asm volatile("s_waitcnt vmcnt(8)" ::: "memory")
#define PR1() __builtin_amdgcn_s_setprio(1)
#define PR0() __builtin_amdgcn_s_setprio(0)

  STA(0, 0, 0);
  STA(0, 1, 0);
  STB(0, 0, 0);
  STB(0, 1, 0);
  STA(1, 0, 1);
  STA(1, 1, 1);
  STB(1, 0, 1);
  STB(1, 1, 1);
  WVM8();
  BARx();

  int a = 0;
  for (int t = 0; t < NT; ++t) {
    const int b = t & 1;
    int a2 = a + 2;
    if (a2 >= 3) a2 -= 3;
    const int kt2 = (t + 2 < NT) ? t + 2 : NT - 1;  // clamped tail restage
    // P1
    DSBq(b);
    DSAq(a, 0);
    STA(a2, 0, kt2);
    BARx();
    WLGx();
    PR1();
    MMq(0);
    PR0();
    BARx();
    // P2
    DSAq(a, 1);
    STA(a2, 1, kt2);
    BARx();
    WLGx();
    PR1();
    MMq(1);
    PR0();
    BARx();
    // P3 (Bs[b] stage-safe: B(t) regs read at P1)
    DSAq(a, 2);
    STB(b, 0, kt2);
    BARx();
    WLGx();
    PR1();
    MMq(2);
    PR0();
    BARx();
    // P4
    DSAq(a, 3);
    STB(b, 1, kt2);
    BARx();
    WLGx();
    PR1();
    MMq(3);
    PR0();
    WVM8();
    BARx();
    ++a;
    if (a == 3) a = 0;
  }
  asm volatile("s_waitcnt vmcnt(0)" ::: "memory");

  const long long orow0 = (long long)bm * 256 + wr * 128 + quad * 4;
  const int ocol0 = bn * 256 + wc * 64 + l16;
  if (out_bf16) {
    ush* Cp = (ush*)C;
#pragma unroll
    for (int mi = 0; mi < 8; ++mi)
#pragma unroll
      for (int ni = 0; ni < 4; ++ni) {
        const int col = ocol0 + ni * 16;
        const float bv = bias ? bias[col] : 0.f;
#pragma unroll
        for (int r = 0; r < 4; ++r) {
          const float o = acc[mi][ni][r] * alpha + bv;
          Cp[(orow0 + mi * 16 + r) * N + col] = f32_to_bf16(o);
        }
      }
  } else {
    float* Cp = (float*)C;
#pragma unroll
    for (int mi = 0; mi < 8; ++mi)
#pragma unroll
      for (int ni = 0; ni < 4; ++ni) {
        const int col = ocol0 + ni * 16;
        const float bv = bias ? bias[col] : 0.f;
#pragma unroll
        for (int r = 0; r < 4; ++r) {
          const float o = acc[mi][ni][r] * alpha + bv;
          Cp[(orow0 + mi * 16 + r) * N + col] = o;
        }
      }
  }
#undef STA
#undef STB
#undef DSAq
#undef DSBq
#undef MMq
#undef BARx
#undef WLGx
#undef WVM8
#undef PR1
#undef PR0
}

// ------------------------------- 128x256 3-buf tile (verified)
// lds = 144KB of smem; bias_row==1 -> bias[row], else bias[col].
__device__ void g128_tile(const ush* __restrict__ A, const ush* __restrict__ B,
                          void* __restrict__ C, const float* __restrict__ bias,
                          int N, int K, float alpha, int out_bf16,
                          int bias_row, int lda, int ldb, int bn, int bm,
                          char* smem) {
  ush (*As)[128][64] = (ush(*)[128][64])smem;            // 48KB
  ush (*Bs)[256][64] = (ush(*)[256][64])(smem + 49152);  // 96KB

  const int tid = threadIdx.x;
  const int lane = tid & 63, wave = tid >> 6;
  const int wr = wave >> 2;
  const int wc = wave & 3;
  const int l16 = lane & 15, quad = lane >> 4;
  const int pc0 = (quad ^ (l16 & 7)) * 8;
  const int pc1 = ((4 + quad) ^ (l16 & 7)) * 8;

  const int srow = tid >> 3;
  const int lch = (tid & 7) ^ (srow & 7);
  const ush* gA0 = A + (long long)(bm * 128 + srow) * lda + lch * 8;
  const ush* gB0 = B + (long long)(bn * 256 + srow) * ldb + lch * 8;

  f32x4 acc[4][4] = {};
  bf16x8 af[2][2];
  bf16x8 bf[4][2];

  const int NT = K >> 6;

#define STG_A(BUF, KT)                                                      \
  do {                                                                      \
    const ush* _s = gA0 + (long long)(KT) * 64;                             \
    char* _d = (char*)&As[BUF][0][0] + wave * 1024;                         \
    load_lds16(_s, _d);                                                     \
    load_lds16(_s + (long long)64 * lda, _d + 8192);                        \
  } while (0)
#define STG_B(BUF, KT, J0, JN)                                              \
  do {                                                                      \
    const ush* _s = gB0 + (long long)(KT) * 64;                             \
    char* _d = (char*)&Bs[BUF][0][0] + wave * 1024;                         \
    _Pragma("unroll") for (int _j = (J0); _j < (JN); ++_j)                  \
        load_lds16(_s + (long long)(_j * 64) * ldb, _d + _j * 8192);        \
  } while (0)
#define DSA(BUF, P)                                                         \
  do {                                                                      \
    _Pragma("unroll") for (int m2 = 0; m2 < 2; ++m2) {                      \
      const ush* _r = &As[BUF][wr * 64 + ((P) * 2 + m2) * 16 + l16][0];     \
      af[m2][0] = *(const bf16x8*)(_r + pc0);                               \
      af[m2][1] = *(const bf16x8*)(_r + pc1);                               \
    }                                                                       \
  } while (0)
#define DSB(BUF)                                                            \
  do {                                                                      \
    _Pragma("unroll") for (int ni = 0; ni < 4; ++ni) {                      \
      const ush* _r = &Bs[BUF][wc * 64 + ni * 16 + l16][0];                 \
      bf[ni][0] = *(const bf16x8*)(_r + pc0);                               \
      bf[ni][1] = *(const bf16x8*)(_r + pc1);                               \
    }                                                                       \
  } while (0)
#define MM(P)                                                               \
  do {                                                                      \
    _Pragma("unroll") for (int m2 = 0; m2 < 2; ++m2)                        \
        _Pragma("unroll") for (int ni = 0; ni < 4; ++ni) {                  \
      f32x4* _a = &acc[(P) * 2 + m2][ni];                                   \
      *_a = __builtin_amdgcn_mfma_f32_16x16x32_bf16(af[m2][0], bf[ni][0],   \
                                                    *_a, 0, 0, 0);          \
      *_a = __builtin_amdgcn_mfma_f32_16x16x32_bf16(af[m2][1], bf[ni][1],   \
                                                    *_a, 0, 0, 0);          \
    }                                                                       \
  } while (0)
#define BAR() __builtin_amdgcn_s_barrier()
#define WLG() asm volatile("s_waitcnt lgkmcnt(0)" ::: "memory")
#define WVM6() asm volatile("s_waitcnt vmcnt(6)" ::: "memory")
#define P1x() __builtin_amdgcn_s_setprio(1)
#define P0x() __builtin_amdgcn_s_setprio(0)

  STG_A(0, 0);
  STG_B(0, 0, 0, 4);
  STG_A(1, 1);
  STG_B(1, 1, 0, 4);
  WVM6();
  BAR();

  int cur = 0;
  for (int t = 0; t < NT; ++t) {
    int b2 = cur + 2;
    if (b2 >= 3) b2 -= 3;
    const int kt = (t + 2 < NT) ? t + 2 : NT - 1;
    // ph0
    DSB(cur);
    DSA(cur, 0);
    STG_A(b2, kt);
    STG_B(b2, kt, 0, 1);
    BAR();
    WLG();
    P1x();
    MM(0);
    P0x();
    BAR();
    // ph1
    DSA(cur, 1);
    STG_B(b2, kt, 1, 4);
    BAR();
    WLG();
    P1x();
    MM(1);
    P0x();
    WVM6();
    BAR();
    ++cur;
    if (cur == 3) cur = 0;
  }
  asm volatile("s_waitcnt vmcnt(0)" ::: "memory");

  const long long orow0 = (long long)bm * 128 + wr * 64 + quad * 4;
  const int ocol0 = bn * 256 + wc * 64 + l16;
  if (out_bf16) {
    ush* Cp = (ush*)C;
#pragma unroll
    for (int mi = 0; mi < 4; ++mi)
#pragma unroll
      for (int ni = 0; ni < 4; ++ni) {
        const int col = ocol0 + ni * 16;
        const float bcol = (bias && !bias_row) ? bias[col] : 0.f;
#pragma unroll
        for (int r = 0; r < 4; ++r) {
          const float bv =
              (bias && bias_row) ? bias[orow0 + mi * 16 + r] : bcol;
          const float o = acc[mi][ni][r] * alpha + bv;
          Cp[(orow0 + mi * 16 + r) * N + col] = f32_to_bf16(o);
        }
      }
  } else {
    float* Cp = (float*)C;
#pragma unroll
    for (int mi = 0; mi < 4; ++mi)
#pragma unroll
      for (int ni = 0; ni < 4; ++ni) {
        const int col = ocol0 + ni * 16;
        const float bcol = (bias && !bias_row) ? bias[col] : 0.f;
#pragma unroll
        for (int r = 0; r < 4; ++r) {
          const float bv =
              (bias && bias_row) ? bias[orow0 + mi * 16 + r] : bcol;
          const float o = acc[mi][ni][r] * alpha + bv;
          Cp[(orow0 + mi * 16 + r) * N + col] = o;
        }
      }
  }
#undef STG_A
#undef STG_B
#undef DSA
#undef DSB
#undef MM
#undef BAR
#undef WLG
#undef WVM6
#undef P1x
#undef P0x
}

// ---------------- standalone wrappers (T1 bijective XCD swizzle, verified)
__global__ __launch_bounds__(512, 2) void k256(
    const ush* __restrict__ A, const ush* __restrict__ B, void* __restrict__ C,
    const float* __restrict__ bias, int N, int K, float alpha, int out_bf16,
    int lda, int ldb, long long sA, long long sB, long long sC) {
  __shared__ __align__(16) char smem[163840];
  const int hw = blockIdx.x + gridDim.x * (blockIdx.y + gridDim.y * blockIdx.z);
  const int nwg = gridDim.x * gridDim.y * gridDim.z;
  const int lg = (hw & 7) * (nwg >> 3) + (hw >> 3);
  const int bn = lg % gridDim.x;
  const int rem = lg / gridDim.x;
  const int bm = rem % gridDim.y;
  const int bz = rem / gridDim.y;
  void* Cb = out_bf16 ? (void*)((ush*)C + (long long)bz * sC)
                      : (void*)((float*)C + (long long)bz * sC);
  g256_tile(A + (long long)bz * sA, B + (long long)bz * sB, Cb, bias, N, K,
            alpha, out_bf16, lda, ldb, bn, bm, smem);
}

__global__ __launch_bounds__(512, 2) void k128(
    const ush* __restrict__ A, const ush* __restrict__ B, void* __restrict__ C,
    const float* __restrict__ bias, int N, int K, float alpha, int out_bf16,
    int bias_row, int lda, int ldb, long long sA, long long sB, long long sC) {
  __shared__ __align__(16) char smem[147456];
  const int hw = blockIdx.x + gridDim.x * (blockIdx.y + gridDim.y * blockIdx.z);
  const int nwg = gridDim.x * gridDim.y * gridDim.z;
  const int lg = (hw & 7) * (nwg >> 3) + (hw >> 3);
  const int bn = lg % gridDim.x;
  const int rem = lg / gridDim.x;
  const int bm = rem % gridDim.y;
  const int bz = rem / gridDim.y;
  void* Cb = out_bf16 ? (void*)((ush*)C + (long long)bz * sC)
                      : (void*)((float*)C + (long long)bz * sC);
  g128_tile(A + (long long)bz * sA, B + (long long)bz * sB, Cb, bias, N, K,
            alpha, out_bf16, bias_row, lda, ldb, bn, bm, smem);
}

// ------------------------------------------------- row softmax (vectorized)
// S: [8192][2048] fp32 -> P bf16. One block/row; float4 x2 in, ushort4 x2 out.
__global__ __launch_bounds__(256) void softmax_rows(
    const float* __restrict__ S, ush* __restrict__ P) {
  const long long row = blockIdx.x;
  const float4* s4 = (const float4*)(S + row * 2048);
  const int t = threadIdx.x;
  float4 a = s4[t], b = s4[t + 256];
  float mx = fmaxf(fmaxf(fmaxf(a.x, a.y), fmaxf(a.z, a.w)),
                   fmaxf(fmaxf(b.x, b.y), fmaxf(b.z, b.w)));
#pragma unroll
  for (int o = 32; o >= 1; o >>= 1) mx = fmaxf(mx, __shfl_xor(mx, o));
  __shared__ float red[4], red2[4];
  if ((t & 63) == 0) red[t >> 6] = mx;
  __syncthreads();
  mx = fmaxf(fmaxf(red[0], red[1]), fmaxf(red[2], red[3]));
  a.x = __expf(a.x - mx);
  a.y = __expf(a.y - mx);
  a.z = __expf(a.z - mx);
  a.w = __expf(a.w - mx);
  b.x = __expf(b.x - mx);
  b.y = __expf(b.y - mx);
  b.z = __expf(b.z - mx);
  b.w = __expf(b.w - mx);
  float sum = (a.x + a.y) + (a.z + a.w) + (b.x + b.y) + (b.z + b.w);
#pragma unroll
  for (int o = 32; o >= 1; o >>= 1) sum += __shfl_xor(sum, o);
  if ((t & 63) == 0) red2[t >> 6] = sum;
  __syncthreads();
  sum = red2[0] + red2[1] + red2[2] + red2[3];
  const float inv = 1.0f / sum;
  ushort4 ua, ub;
  ua.x = f32_to_bf16(a.x * inv);
  ua.y = f32_to_bf16(a.y * inv);
  ua.z = f32_to_bf16(a.z * inv);
  ua.w = f32_to_bf16(a.w * inv);
  ub.x = f32_to_bf16(b.x * inv);
  ub.y = f32_to_bf16(b.y * inv);
  ub.z = f32_to_bf16(b.z * inv);
  ub.w = f32_to_bf16(b.w * inv);
  ushort4* p4 = (ushort4*)(P + row * 2048);
  p4[t] = ua;
  p4[t + 256] = ub;
}

// ----------------------------------------------------------------- launcher
extern "C" void kernel_launch(void* const* d_in, const int* in_sizes, int n_in,
                              void* d_out, int out_size, void* d_ws,
                              size_t ws_size, hipStream_t stream) {
  const float* x = (const float*)d_in[0];
  const float* wq = (const float*)d_in[1];
  const float* bq = (const float*)d_in[2];
  const float* wk = (const float*)d_in[3];
  const float* bk = (const float*)d_in[4];
  const float* wv = (const float*)d_in[5];
  const float* bv = (const float*)d_in[6];
  const float* wo = (const float*)d_in[7];
  const float* bo = (const float*)d_in[8];
  float* out = (float*)d_out;
  char* ws = (char*)d_ws;
  const size_t MB = 1ull << 20;

  ush* xb  = (ush*)(ws + 0);        // 16MB, later O
  ush* wqk = (ush*)(ws + 16 * MB);  // 4MB [2048][1024]
  ush* wvb = (ush*)(ws + 20 * MB);  // 2MB
  ush* wob = (ush*)(ws + 22 * MB);  // 2MB
  ush* QKm = (ush*)(ws + 24 * MB);  // 32MB [8192][2048]
  ush* VT  = (ush*)(ws + 56 * MB);  // 16MB [1024][8192]
  float* S   = (float*)(ws + 72 * MB);  // 64MB
  float* bqk = (float*)(ws + 72 * MB);  // 8KB, dies before S is written
  ush* P = QKm;                         // 32MB over QK
  ush* O = xb;                          // 16MB over x_bf16

  // 1) fused prep: all casts + bias concat
  prep<<<dim3(12290), dim3(256), 0, stream>>>(
      (const float4*)x, (const float4*)wq, (const float4*)wk,
      (const float4*)wv, (const float4*)wo, (const float4*)bq,
      (const float4*)bk, (ushort4*)xb, (ushort4*)wqk, (ushort4*)wvb,
      (ushort4*)wob, (float4*)bqk);

  // 2) fused QK projection: [8192,2048] = x_bf16 @ [wq;wk]^T + bqk
  //    256dp engine, grid 8x32 = 256 blocks = 1 full round
  k256<<<dim3(8, 32, 1), dim3(512), 0, stream>>>(
      xb, wqk, QKm, bqk, 2048, 1024, 1.f, 1, 1024, 1024, 0, 0, 0);

  // 3) VT[d][s] = sum_k w_v[d,k] x[s,k] + bv[d] (per-ROW bias)
  //    128x256 engine, grid 32x8 = 256 blocks
  k128<<<dim3(32, 8, 1), dim3(512), 0, stream>>>(
      wvb, xb, VT, bv, 8192, 1024, 1.f, 1, 1, 1024, 1024, 0, 0, 0);

  // 4) S = Q K^T / 32, fp32, batched over 4 (Q,K are column slices of QKm)
  //    256dp engine, grid 8x8x4 = 256 blocks = 1 full round
  k256<<<dim3(8, 8, 4), dim3(512), 0, stream>>>(
      QKm, QKm + 1024, S, nullptr, 2048, 1024, 0.03125f, 0, 2048, 2048,
      2048ll * 2048, 2048ll * 2048, 2048ll * 2048);

  // 5) P = softmax rows of S (bf16), vectorized
  softmax_rows<<<dim3(8192), dim3(256), 0, stream>>>(S, P);

  // 6) O = P @ V via VT (128x256), batched over 4; grid 4x16x4 = 256 blocks
  k128<<<dim3(4, 16, 4), dim3(512), 0, stream>>>(
      P, VT, O, nullptr, 1024, 2048, 1.f, 1, 0, 2048, 8192, 2048ll * 2048,
      2048ll, 2048ll * 1024);

  // 7) out = O @ Wo^T + bo (fp32); grid 4x64 = 256 blocks
  k128<<<dim3(4, 64, 1), dim3(512), 0, stream>>>(
      O, wob, out, bo, 1024, 1024, 1.f, 0, 0, 1024, 1024, 0, 0, 0);
}